// Round 1
// baseline (256.055 us; speedup 1.0000x reference)
//
#include <hip/hip_runtime.h>

// Problem constants
#define B_ 32
#define N_ 8192
#define D_ 128
#define H_ 128
#define R_ (B_ * N_)  // 262144 rows total

typedef _Float16 f16;
typedef __attribute__((ext_vector_type(4))) _Float16 f16x4;
typedef __attribute__((ext_vector_type(8))) _Float16 f16x8;
typedef __attribute__((ext_vector_type(4))) float f32x4;

// Workspace layout (bytes)
//   [0, 64MB)          h_ws  : R_*128 f16
//   [+0x18000)         wpack : 3*128*128 f16  (MFMA B-fragment order)
//   [+1MB)             g_ws  : R_ fp32 gate scores
//   [+128B)            mx[32], inv_denom[32]
static constexpr size_t HWS_OFF   = 0;
static constexpr size_t WPACK_OFF = (size_t)R_ * 128 * 2;          // 67108864
static constexpr size_t GWS_OFF   = WPACK_OFF + 3 * 128 * 128 * 2; // +98304
static constexpr size_t MX_OFF    = GWS_OFF + (size_t)R_ * 4;      // +1MB
static constexpr size_t INV_OFF   = MX_OFF + 32 * 4;

__device__ __forceinline__ float silu_f(float v) {
    return v / (1.0f + __expf(-v));
}

__device__ __forceinline__ f32x4 mfma16(f16x8 a, f16x8 b, f32x4 c) {
    return __builtin_amdgcn_mfma_f32_16x16x32_f16(a, b, c, 0, 0, 0);
}

// ---------------------------------------------------------------------------
// K0: prepack Wg1, Wn1, Wn2 (fp32, [k][n] row-major 128x128) into fp16 MFMA
// B-fragment order: out[m*16384 + ((nt*4+kc)*64 + lane)*8 + j]
//   = W[(kc*32 + (lane>>4)*8 + j) * 128 + (nt*16 + (lane&15))]
// ---------------------------------------------------------------------------
__global__ void k0_prepack(const float* __restrict__ Wg1,
                           const float* __restrict__ Wn1,
                           const float* __restrict__ Wn2,
                           f16* __restrict__ wp) {
    int tid = blockIdx.x * 256 + threadIdx.x;  // 0..49151
    int m    = tid >> 14;
    int r    = tid & 16383;
    int j    = r & 7;
    int lane = (r >> 3) & 63;
    int kc   = (r >> 9) & 3;
    int nt   = r >> 11;
    int k = kc * 32 + (lane >> 4) * 8 + j;
    int n = nt * 16 + (lane & 15);
    const float* W = (m == 0) ? Wg1 : (m == 1) ? Wn1 : Wn2;
    wp[tid] = (f16)W[k * 128 + n];
}

// ---------------------------------------------------------------------------
// K1: fused 3-GEMM. Grid 512 blocks x 512 threads; each block loops 8 tiles
// of 64 rows. Wave w (0..7) owns output-column stripe [w*16, w*16+16).
// ---------------------------------------------------------------------------
__global__ __launch_bounds__(512) void k1_fused_gemm(
        const float* __restrict__ x,
        const float* __restrict__ bg1, const float* __restrict__ wg2,
        const float* __restrict__ bg2,
        const float* __restrict__ bn1, const float* __restrict__ bn2,
        const f16* __restrict__ wp,
        f16* __restrict__ hws, float* __restrict__ gws) {
    // LDS: padded (+8 halves) so A-frag ds_read_b128 rows land on distinct banks
    __shared__ f16 xlds[64 * 136];
    __shared__ f16 h1lds[64 * 136];
    __shared__ float gpart[8][64];

    const int tid  = threadIdx.x;
    const int w    = tid >> 6;    // wave id = n-tile id
    const int lane = tid & 63;
    const int q    = lane >> 4;
    const int c    = lane & 15;
    const int colg = w * 16 + c;  // this lane's output column

    // B-fragments: 3 matrices x 4 k-chunks, resident in registers
    const f16x8* wpv = (const f16x8*)wp;  // 2048 f16x8 per matrix
    f16x8 fg1[4], fn1[4], fn2[4];
#pragma unroll
    for (int kc = 0; kc < 4; ++kc) {
        int base = (w * 4 + kc) * 64 + lane;
        fg1[kc] = wpv[base];
        fn1[kc] = wpv[2048 + base];
        fn2[kc] = wpv[4096 + base];
    }
    const float bg1v = bg1[colg];
    const float bn1v = bn1[colg];
    const float bn2v = bn2[colg];
    const float wg2v = wg2[colg];
    const float bg2v = bg2[0];

    for (int it = 0; it < 8; ++it) {
        const long tile = (long)blockIdx.x * 8 + it;
        const long tb   = tile * 64;  // first global row of this tile

        __syncthreads();  // protect xlds/h1lds/gpart from previous iteration

        // ---- stage x tile (64 rows x 128 cols fp32 -> fp16 LDS) ----
        const float4* xg = ((const float4*)x) + tb * 32;
#pragma unroll
        for (int s = 0; s < 4; ++s) {
            int i   = s * 512 + tid;   // 0..2047
            int row = i >> 5;
            int c4  = i & 31;
            float4 v = xg[i];
            f16x4 hv = {(f16)v.x, (f16)v.y, (f16)v.z, (f16)v.w};
            *(f16x4*)&xlds[row * 136 + c4 * 4] = hv;
        }
        __syncthreads();

        // ---- GEMM gate1 + GEMM n1 (share A-fragments) ----
#pragma unroll
        for (int mt = 0; mt < 4; ++mt) {
            f16x8 a[4];
            const int arow = mt * 16 + c;
#pragma unroll
            for (int kc = 0; kc < 4; ++kc)
                a[kc] = *(const f16x8*)&xlds[arow * 136 + kc * 32 + q * 8];

            f32x4 ag = {0.f, 0.f, 0.f, 0.f};
            f32x4 an = {0.f, 0.f, 0.f, 0.f};
#pragma unroll
            for (int kc = 0; kc < 4; ++kc) {
                ag = mfma16(a[kc], fg1[kc], ag);
                an = mfma16(a[kc], fn1[kc], an);
            }
            // gate epilogue: silu, * wg2[col], reduce across 16 cols
            float gp[4];
#pragma unroll
            for (int r = 0; r < 4; ++r)
                gp[r] = silu_f(ag[r] + bg1v) * wg2v;
#pragma unroll
            for (int mask = 1; mask < 16; mask <<= 1) {
#pragma unroll
                for (int r = 0; r < 4; ++r)
                    gp[r] += __shfl_xor(gp[r], mask);
            }
            if (c == 0) {
#pragma unroll
                for (int r = 0; r < 4; ++r)
                    gpart[w][mt * 16 + q * 4 + r] = gp[r];
            }
            // n1 epilogue: silu -> h1 LDS (C-layout -> A-layout round trip)
#pragma unroll
            for (int r = 0; r < 4; ++r) {
                int row = mt * 16 + q * 4 + r;
                h1lds[row * 136 + colg] = (f16)silu_f(an[r] + bn1v);
            }
        }
        __syncthreads();

        // ---- finalize gate scores ----
        if (tid < 64) {
            float g = bg2v;
#pragma unroll
            for (int w2 = 0; w2 < 8; ++w2) g += gpart[w2][tid];
            gws[tb + tid] = g;
        }

        // ---- GEMM n2: h = h1 @ Wn2 + bn2 -> global fp16 ----
#pragma unroll
        for (int mt = 0; mt < 4; ++mt) {
            f16x8 a[4];
            const int arow = mt * 16 + c;
#pragma unroll
            for (int kc = 0; kc < 4; ++kc)
                a[kc] = *(const f16x8*)&h1lds[arow * 136 + kc * 32 + q * 8];
            f32x4 acc = {0.f, 0.f, 0.f, 0.f};
#pragma unroll
            for (int kc = 0; kc < 4; ++kc)
                acc = mfma16(a[kc], fn2[kc], acc);
#pragma unroll
            for (int r = 0; r < 4; ++r) {
                int row = mt * 16 + q * 4 + r;
                hws[(tb + row) * 128 + colg] = (f16)(acc[r] + bn2v);
            }
        }
    }
}

// ---------------------------------------------------------------------------
// K2: per-batch softmax stats (max, 1/sum(exp)); also zeroes d_out.
// One block per b, 256 threads.
// ---------------------------------------------------------------------------
__global__ void k2_softmax_stats(const float* __restrict__ gws,
                                 float* __restrict__ mx,
                                 float* __restrict__ inv,
                                 float* __restrict__ out) {
    const int b = blockIdx.x;
    const int t = threadIdx.x;
    const float* g = gws + (long)b * N_;

    float m = -1e30f;
    for (int i = t; i < N_; i += 256) m = fmaxf(m, g[i]);
#pragma unroll
    for (int mask = 1; mask < 64; mask <<= 1) m = fmaxf(m, __shfl_xor(m, mask));
    __shared__ float redm[4];
    if ((t & 63) == 0) redm[t >> 6] = m;
    __syncthreads();
    m = fmaxf(fmaxf(redm[0], redm[1]), fmaxf(redm[2], redm[3]));

    float s = 0.f;
    for (int i = t; i < N_; i += 256) s += __expf(g[i] - m);
#pragma unroll
    for (int mask = 1; mask < 64; mask <<= 1) s += __shfl_xor(s, mask);
    __shared__ float reds[4];
    if ((t & 63) == 0) reds[t >> 6] = s;
    __syncthreads();
    if (t == 0) {
        float d = reds[0] + reds[1] + reds[2] + reds[3];
        mx[b]  = m;
        inv[b] = 1.0f / d;
    }
    if (t < 128) out[b * 128 + t] = 0.f;
}

// ---------------------------------------------------------------------------
// K3: weighted pooling. Grid (32 chunks, 32 b) x 256 threads.
// Each block: 256 rows; float4 (8-half) loads; partial sums -> atomicAdd.
// ---------------------------------------------------------------------------
__global__ void k3_pool(const float* __restrict__ gws,
                        const f16* __restrict__ hws,
                        const float* __restrict__ mx,
                        const float* __restrict__ inv,
                        float* __restrict__ out) {
    const int ch = blockIdx.x;
    const int b  = blockIdx.y;
    const int t  = threadIdx.x;
    const long base = (long)b * N_ + (long)ch * 256;

    __shared__ float wbuf[256];
    __shared__ float part[16][128];

    wbuf[t] = __expf(gws[base + t] - mx[b]) * inv[b];
    __syncthreads();

    const int cg = t & 15;   // col-group: 8 cols each
    const int rg = t >> 4;   // row-group: 16 rows each
    const float4* hp = (const float4*)(hws + base * 128);

    float acc[8] = {0.f, 0.f, 0.f, 0.f, 0.f, 0.f, 0.f, 0.f};
#pragma unroll
    for (int r = 0; r < 16; ++r) {
        int rl = rg * 16 + r;
        float4 v = hp[rl * 16 + cg];
        float wv = wbuf[rl];
        const f16* hv = (const f16*)&v;
#pragma unroll
        for (int j = 0; j < 8; ++j) acc[j] += wv * (float)hv[j];
    }
#pragma unroll
    for (int j = 0; j < 8; ++j) part[rg][cg * 8 + j] = acc[j];
    __syncthreads();

    if (t < 128) {
        float s = 0.f;
#pragma unroll
        for (int r2 = 0; r2 < 16; ++r2) s += part[r2][t];
        atomicAdd(&out[b * 128 + t], s);
    }
}

// ---------------------------------------------------------------------------
extern "C" void kernel_launch(void* const* d_in, const int* in_sizes, int n_in,
                              void* d_out, int out_size, void* d_ws, size_t ws_size,
                              hipStream_t stream) {
    const float* x   = (const float*)d_in[0];
    const float* Wg1 = (const float*)d_in[1];
    const float* bg1 = (const float*)d_in[2];
    const float* Wg2 = (const float*)d_in[3];
    const float* bg2 = (const float*)d_in[4];
    const float* Wn1 = (const float*)d_in[5];
    const float* bn1 = (const float*)d_in[6];
    const float* Wn2 = (const float*)d_in[7];
    const float* bn2 = (const float*)d_in[8];
    float* out = (float*)d_out;

    char* ws = (char*)d_ws;
    f16*   hws = (f16*)(ws + HWS_OFF);
    f16*   wp  = (f16*)(ws + WPACK_OFF);
    float* gws = (float*)(ws + GWS_OFF);
    float* mx  = (float*)(ws + MX_OFF);
    float* inv = (float*)(ws + INV_OFF);

    k0_prepack<<<192, 256, 0, stream>>>(Wg1, Wn1, Wn2, wp);
    k1_fused_gemm<<<512, 512, 0, stream>>>(x, bg1, Wg2, bg2, bn1, bn2, wp, hws, gws);
    k2_softmax_stats<<<32, 256, 0, stream>>>(gws, mx, inv, out);
    k3_pool<<<dim3(32, 32), 256, 0, stream>>>(gws, hws, mx, inv, out);
}

// Round 2
// 223.358 us; speedup vs baseline: 1.1464x; 1.1464x over previous
//
#include <hip/hip_runtime.h>

// Problem constants
#define B_ 32
#define N_ 8192
#define D_ 128
#define H_ 128
#define R_ (B_ * N_)  // 262144 rows total

typedef _Float16 f16;
typedef __attribute__((ext_vector_type(4))) _Float16 f16x4;
typedef __attribute__((ext_vector_type(8))) _Float16 f16x8;
typedef __attribute__((ext_vector_type(4))) float f32x4;

// Workspace layout (bytes)
static constexpr size_t WPACK_OFF = 0;                        // 3*128*128 f16 = 98304
static constexpr size_t VPART_OFF = 98304;                    // 512*128 f32  = 262144
static constexpr size_t SPART_OFF = VPART_OFF + 512 * 128 * 4; // 512 f32

__device__ __forceinline__ float silu_f(float v) {
    return v / (1.0f + __expf(-v));
}

__device__ __forceinline__ f32x4 mfma16(f16x8 a, f16x8 b, f32x4 c) {
    return __builtin_amdgcn_mfma_f32_16x16x32_f16(a, b, c, 0, 0, 0);
}

// ---------------------------------------------------------------------------
// K0: prepack Wg1, Wn1, Wn2 (fp32 row-major [k][n] 128x128) into fp16 MFMA
// fragment order (A/B symmetric): frag[(nt*4+kc)*64 + lane][j]
//   = W[(kc*32 + (lane>>4)*8 + j)][nt*16 + (lane&15)]
// ---------------------------------------------------------------------------
__global__ void k0_prepack(const float* __restrict__ Wg1,
                           const float* __restrict__ Wn1,
                           const float* __restrict__ Wn2,
                           f16* __restrict__ wp) {
    int tid = blockIdx.x * 256 + threadIdx.x;  // 0..49151
    int m    = tid >> 14;
    int r    = tid & 16383;
    int j    = r & 7;
    int lane = (r >> 3) & 63;
    int kc   = (r >> 9) & 3;
    int nt   = r >> 11;
    int k = kc * 32 + (lane >> 4) * 8 + j;
    int n = nt * 16 + (lane & 15);
    const float* W = (m == 0) ? Wg1 : (m == 1) ? Wn1 : Wn2;
    wp[tid] = (f16)W[k * 128 + n];
}

// ---------------------------------------------------------------------------
// K1: fully fused. 512 blocks x 512 threads; each block owns 512 rows
// (8 tiles of 64) of ONE batch, computes gate scores + h rows, and
// accumulates V[128] = sum exp(g)*h and S = sum exp(g) into a per-block
// partial. MFMA issued transposed (W as A-operand) so outputs land as
// [col][row]: gate reduce = 2 shuffles, h1 transform = contiguous b64
// writes, V accumulate = 4 regs/lane.
// LDS x/h1 layout: fragment order with XOR swizzle:
//   halfidx(row=mt*16+c, k=kc*32+q*8+j) =
//     ((mt*4+kc)*64 + q*16 + (c ^ ((kc&1)*4+q)))*8 + j
// Reads are lane-contiguous ds_read_b128 (conflict-free); writes 2-way free.
// ---------------------------------------------------------------------------
__global__ __launch_bounds__(512) void k1_fused(
        const float* __restrict__ x,
        const float* __restrict__ bg1, const float* __restrict__ wg2,
        const float* __restrict__ bg2, const float* __restrict__ bn1,
        const f16* __restrict__ wp,
        float* __restrict__ vpart, float* __restrict__ spart) {
    __shared__ f16 xlds[64 * 128];
    __shared__ f16 h1lds[64 * 128];
    __shared__ float gpart[8][64];
    __shared__ float ebuf[64];

    const int tid  = threadIdx.x;
    const int w    = tid >> 6;    // wave id = 16-col stripe
    const int lane = tid & 63;
    const int q    = lane >> 4;
    const int c    = lane & 15;

    // Weight fragments resident in registers (layout serves A and B roles)
    const f16x8* wpv = (const f16x8*)wp;
    f16x8 fg1[4], fn1[4], fn2[4];
#pragma unroll
    for (int kc = 0; kc < 4; ++kc) {
        int base = (w * 4 + kc) * 64 + lane;
        fg1[kc] = wpv[base];
        fn1[kc] = wpv[2048 + base];
        fn2[kc] = wpv[4096 + base];
    }
    // Per-lane bias/weight vectors for cols w*16+q*4+r
    float bg1q[4], wg2q[4], bn1q[4];
#pragma unroll
    for (int r = 0; r < 4; ++r) {
        int col = w * 16 + q * 4 + r;
        bg1q[r] = bg1[col];
        wg2q[r] = wg2[col];
        bn1q[r] = bn1[col];
    }
    const float bg2v = bg2[0];

    // Swizzled per-lane LDS read offsets (in halves) for frag reads
    const int loh_e = (q * 16 + (c ^ q)) * 8;        // kc even
    const int loh_o = (q * 16 + (c ^ (q | 4))) * 8;  // kc odd
    // h1 write target (constant part, in halves)
    const int kc2 = w >> 1;
    const int q2  = (w & 1) * 2 + (q >> 1);
    const int v2  = ((kc2 & 1) << 2) | q2;
    const int h1w_base = kc2 * 512 + (q2 * 16 + (c ^ v2)) * 8 + (q & 1) * 4;

    float V[4] = {0.f, 0.f, 0.f, 0.f};
    float Sl = 0.f;  // only wave0's lanes accumulate

    const long rowbase = (long)blockIdx.x * 512;

    float4 pre[4];
    {
        const float4* xg = (const float4*)x + rowbase * 32;
#pragma unroll
        for (int s = 0; s < 4; ++s) pre[s] = xg[s * 512 + tid];
    }

    for (int t = 0; t < 8; ++t) {
        __syncthreads();  // A: prev n2 reads of h1lds / prev reads of xlds done

        // ---- stage prefetched x tile into swizzled frag-order LDS ----
#pragma unroll
        for (int s = 0; s < 4; ++s) {
            int e   = s * 512 + tid;      // 0..2047 float4s
            int row = e >> 5, c4 = e & 31;
            int mt = row >> 4, cc = row & 15;
            int kc = c4 >> 3, qq = (c4 >> 1) & 3, j = (c4 & 1) * 4;
            int sw = (c4 >> 1) & 7;       // = (kc&1)*4 + qq
            int hidx = ((mt * 4 + kc) * 64 + qq * 16 + (cc ^ sw)) * 8 + j;
            float4 vv = pre[s];
            f16x4 hv = {(f16)vv.x, (f16)vv.y, (f16)vv.z, (f16)vv.w};
            *(f16x4*)&xlds[hidx] = hv;
        }
        __syncthreads();  // B: xlds ready

        // ---- prefetch next tile (overlaps gate/n1 compute) ----
        if (t < 7) {
            const float4* xg = (const float4*)x + (rowbase + (t + 1) * 64) * 32;
#pragma unroll
            for (int s = 0; s < 4; ++s) pre[s] = xg[s * 512 + tid];
        }

        // ---- gate1 + n1 (transposed: D[col][row]) ----
#pragma unroll
        for (int mt = 0; mt < 4; ++mt) {
            f16x8 a[4];
#pragma unroll
            for (int kc = 0; kc < 4; ++kc)
                a[kc] = *(const f16x8*)&xlds[(mt * 4 + kc) * 512 +
                                             ((kc & 1) ? loh_o : loh_e)];
            f32x4 ag = {0.f, 0.f, 0.f, 0.f};
            f32x4 an = {0.f, 0.f, 0.f, 0.f};
#pragma unroll
            for (int kc = 0; kc < 4; ++kc) {
                ag = mfma16(fg1[kc], a[kc], ag);
                an = mfma16(fn1[kc], a[kc], an);
            }
            // h1 epilogue: lane holds h1[row=mt*16+c][col=w*16+q*4+r]
            f16x4 h4;
#pragma unroll
            for (int r = 0; r < 4; ++r) h4[r] = (f16)silu_f(an[r] + bn1q[r]);
            *(f16x4*)&h1lds[mt * 2048 + h1w_base] = h4;
            // gate partial: sum over this lane's 4 cols, then over q (cols)
            float p = 0.f;
#pragma unroll
            for (int r = 0; r < 4; ++r)
                p += silu_f(ag[r] + bg1q[r]) * wg2q[r];
            p += __shfl_xor(p, 16);
            p += __shfl_xor(p, 32);
            if (lane < 16) gpart[w][mt * 16 + lane] = p;
        }
        __syncthreads();  // C: gpart + h1lds ready

        // ---- wave0: finalize gate scores, exp, denom partial ----
        if (tid < 64) {
            float g = bg2v;
#pragma unroll
            for (int w2 = 0; w2 < 8; ++w2) g += gpart[w2][tid];
            float e = __expf(g);
            ebuf[tid] = e;
            Sl += e;
        }
        __syncthreads();  // D: ebuf ready

        // ---- n2 (transposed) + weighted V accumulation ----
#pragma unroll
        for (int mt = 0; mt < 4; ++mt) {
            f16x8 b[4];
#pragma unroll
            for (int kc = 0; kc < 4; ++kc)
                b[kc] = *(const f16x8*)&h1lds[(mt * 4 + kc) * 512 +
                                              ((kc & 1) ? loh_o : loh_e)];
            f32x4 acc = {0.f, 0.f, 0.f, 0.f};
#pragma unroll
            for (int kc = 0; kc < 4; ++kc)
                acc = mfma16(fn2[kc], b[kc], acc);
            float e = ebuf[mt * 16 + c];
#pragma unroll
            for (int r = 0; r < 4; ++r) V[r] += e * acc[r];
        }
    }

    // ---- block-level reductions ----
#pragma unroll
    for (int m = 1; m < 16; m <<= 1) {
#pragma unroll
        for (int r = 0; r < 4; ++r) V[r] += __shfl_xor(V[r], m);
    }
    if ((lane & 15) == 0) {
        float4 o = {V[0], V[1], V[2], V[3]};
        *(float4*)&vpart[(long)blockIdx.x * 128 + w * 16 + q * 4] = o;
    }
    if (w == 0) {
#pragma unroll
        for (int m = 1; m < 64; m <<= 1) Sl += __shfl_xor(Sl, m);
        if (lane == 0) spart[blockIdx.x] = Sl;
    }
}

// ---------------------------------------------------------------------------
// K2: combine per-block partials. 32 blocks (batch) x 128 threads (col).
// 16 blocks per batch. bn2 folded in here (sum attn == 1).
// ---------------------------------------------------------------------------
__global__ void k2_combine(const float* __restrict__ vpart,
                           const float* __restrict__ spart,
                           const float* __restrict__ bn2,
                           float* __restrict__ out) {
    const int b = blockIdx.x;
    const int j = threadIdx.x;
    float v = 0.f, s = 0.f;
#pragma unroll
    for (int k = 0; k < 16; ++k) {
        v += vpart[(long)(b * 16 + k) * 128 + j];
        s += spart[b * 16 + k];
    }
    out[b * 128 + j] = v / s + bn2[j];
}

// ---------------------------------------------------------------------------
extern "C" void kernel_launch(void* const* d_in, const int* in_sizes, int n_in,
                              void* d_out, int out_size, void* d_ws, size_t ws_size,
                              hipStream_t stream) {
    const float* x   = (const float*)d_in[0];
    const float* Wg1 = (const float*)d_in[1];
    const float* bg1 = (const float*)d_in[2];
    const float* Wg2 = (const float*)d_in[3];
    const float* bg2 = (const float*)d_in[4];
    const float* Wn1 = (const float*)d_in[5];
    const float* bn1 = (const float*)d_in[6];
    const float* Wn2 = (const float*)d_in[7];
    const float* bn2 = (const float*)d_in[8];
    float* out = (float*)d_out;

    char* ws = (char*)d_ws;
    f16*   wp    = (f16*)(ws + WPACK_OFF);
    float* vpart = (float*)(ws + VPART_OFF);
    float* spart = (float*)(ws + SPART_OFF);

    k0_prepack<<<192, 256, 0, stream>>>(Wg1, Wn1, Wn2, wp);
    k1_fused<<<512, 512, 0, stream>>>(x, bg1, Wg2, bg2, bn1, wp, vpart, spart);
    k2_combine<<<32, 128, 0, stream>>>(vpart, spart, bn2, out);
}

// Round 3
// 221.247 us; speedup vs baseline: 1.1573x; 1.0095x over previous
//
#include <hip/hip_runtime.h>

// Problem constants
#define B_ 32
#define N_ 8192
#define D_ 128
#define H_ 128
#define R_ (B_ * N_)  // 262144 rows total

#define NBLK 1024     // K1 grid
#define TILES 4       // 64-row tiles per block (NBLK*TILES*64 == R_)

typedef _Float16 f16;
typedef __attribute__((ext_vector_type(4))) _Float16 f16x4;
typedef __attribute__((ext_vector_type(8))) _Float16 f16x8;
typedef __attribute__((ext_vector_type(4))) float f32x4;

// Workspace layout (bytes)
static constexpr size_t WPACK_OFF = 0;                          // 3*128*128 f16
static constexpr size_t VPART_OFF = 98304;                      // NBLK*128 f32
static constexpr size_t SPART_OFF = VPART_OFF + (size_t)NBLK * 128 * 4;

__device__ __forceinline__ float silu_f(float v) {
    // v_rcp_f32 instead of full-precision divide sequence (~12 inst saved)
    return v * __builtin_amdgcn_rcpf(1.0f + __expf(-v));
}

__device__ __forceinline__ f32x4 mfma16(f16x8 a, f16x8 b, f32x4 c) {
    return __builtin_amdgcn_mfma_f32_16x16x32_f16(a, b, c, 0, 0, 0);
}

// ---------------------------------------------------------------------------
// K0: prepack Wg1, Wn1, Wn2 (fp32 row-major [k][n] 128x128) into fp16 MFMA
// fragment order (A/B symmetric): frag[(nt*4+kc)*64 + lane][j]
//   = W[(kc*32 + (lane>>4)*8 + j)][nt*16 + (lane&15)]
// ---------------------------------------------------------------------------
__global__ void k0_prepack(const float* __restrict__ Wg1,
                           const float* __restrict__ Wn1,
                           const float* __restrict__ Wn2,
                           f16* __restrict__ wp) {
    int tid = blockIdx.x * 256 + threadIdx.x;  // 0..49151
    int m    = tid >> 14;
    int r    = tid & 16383;
    int j    = r & 7;
    int lane = (r >> 3) & 63;
    int kc   = (r >> 9) & 3;
    int nt   = r >> 11;
    int k = kc * 32 + (lane >> 4) * 8 + j;
    int n = nt * 16 + (lane & 15);
    const float* W = (m == 0) ? Wg1 : (m == 1) ? Wn1 : Wn2;
    wp[tid] = (f16)W[k * 128 + n];
}

// ---------------------------------------------------------------------------
// K1: fully fused. NBLK blocks x 512 threads; block owns TILES*64 rows of one
// batch; accumulates V[128] = sum exp(g)*h and S = sum exp(g) partials.
// Transposed MFMA (W as A-operand): D[col][row].
// Only 2 barriers/tile:
//   [staging writes xlds] B [gate/n1: read xlds, write h1lds+gpart] C
//   [finalize: read gpart (all waves, redundant); n2: read h1lds; V accum]
// C(t-1) orders xlds reads before staging(t); B(t) orders gpart/h1lds
// reads (finalize/n2 of t-1) before their overwrite in gate/n1(t).
// ---------------------------------------------------------------------------
__global__ __launch_bounds__(512) void k1_fused(
        const float* __restrict__ x,
        const float* __restrict__ bg1, const float* __restrict__ wg2,
        const float* __restrict__ bg2, const float* __restrict__ bn1,
        const f16* __restrict__ wp,
        float* __restrict__ vpart, float* __restrict__ spart) {
    __shared__ f16 xlds[64 * 128];
    __shared__ f16 h1lds[64 * 128];
    __shared__ float gpart[8][64];

    const int tid  = threadIdx.x;
    const int w    = tid >> 6;    // wave id = 16-col stripe
    const int lane = tid & 63;
    const int q    = lane >> 4;
    const int c    = lane & 15;

    // Weight fragments resident in registers (layout serves A and B roles)
    const f16x8* wpv = (const f16x8*)wp;
    f16x8 fg1[4], fn1[4], fn2[4];
#pragma unroll
    for (int kc = 0; kc < 4; ++kc) {
        int base = (w * 4 + kc) * 64 + lane;
        fg1[kc] = wpv[base];
        fn1[kc] = wpv[2048 + base];
        fn2[kc] = wpv[4096 + base];
    }
    float bg1q[4], wg2q[4], bn1q[4];
#pragma unroll
    for (int r = 0; r < 4; ++r) {
        int col = w * 16 + q * 4 + r;
        bg1q[r] = bg1[col];
        wg2q[r] = wg2[col];
        bn1q[r] = bn1[col];
    }
    const float bg2v = bg2[0];

    // Swizzled per-lane LDS read offsets (halves) for frag reads
    const int loh_e = (q * 16 + (c ^ q)) * 8;        // kc even
    const int loh_o = (q * 16 + (c ^ (q | 4))) * 8;  // kc odd
    // h1 write target (constant part, halves)
    const int kc2 = w >> 1;
    const int q2  = (w & 1) * 2 + (q >> 1);
    const int v2  = ((kc2 & 1) << 2) | q2;
    const int h1w_base = kc2 * 512 + (q2 * 16 + (c ^ v2)) * 8 + (q & 1) * 4;

    // Staging destinations (loop-invariant)
    f16* sdst[4];
#pragma unroll
    for (int s = 0; s < 4; ++s) {
        int e   = s * 512 + tid;      // 0..2047 float4s
        int row = e >> 5, c4 = e & 31;
        int mt = row >> 4, cc = row & 15;
        int kc = c4 >> 3, qq = (c4 >> 1) & 3, j = (c4 & 1) * 4;
        int sw = (c4 >> 1) & 7;       // = (kc&1)*4 + qq
        sdst[s] = &xlds[((mt * 4 + kc) * 64 + qq * 16 + (cc ^ sw)) * 8 + j];
    }

    float V[4] = {0.f, 0.f, 0.f, 0.f};
    float Sl = 0.f;  // wave0/q==0 lanes accumulate denom

    const long rowbase = (long)blockIdx.x * (TILES * 64);
    const float4* xg = (const float4*)x + rowbase * 32;

    float4 pre[4];
#pragma unroll
    for (int s = 0; s < 4; ++s) pre[s] = xg[s * 512 + tid];

    for (int t = 0; t < TILES; ++t) {
        // ---- stage prefetched x tile into swizzled frag-order LDS ----
#pragma unroll
        for (int s = 0; s < 4; ++s) {
            float4 vv = pre[s];
            f16x4 hv = {(f16)vv.x, (f16)vv.y, (f16)vv.z, (f16)vv.w};
            *(f16x4*)sdst[s] = hv;
        }
        __syncthreads();  // B: xlds ready (also: prev finalize/n2 done)

        // ---- prefetch next tile (overlaps gate/n1 compute) ----
        if (t < TILES - 1) {
            const float4* xn = xg + (t + 1) * 2048;
#pragma unroll
            for (int s = 0; s < 4; ++s) pre[s] = xn[s * 512 + tid];
        }

        // ---- gate1 + n1 (transposed: D[col][row]) ----
#pragma unroll
        for (int mt = 0; mt < 4; ++mt) {
            f16x8 a[4];
#pragma unroll
            for (int kc = 0; kc < 4; ++kc)
                a[kc] = *(const f16x8*)&xlds[(mt * 4 + kc) * 512 +
                                             ((kc & 1) ? loh_o : loh_e)];
            f32x4 ag = {0.f, 0.f, 0.f, 0.f};
            f32x4 an = {0.f, 0.f, 0.f, 0.f};
#pragma unroll
            for (int kc = 0; kc < 4; ++kc) {
                ag = mfma16(fg1[kc], a[kc], ag);
                an = mfma16(fn1[kc], a[kc], an);
            }
            // h1: lane holds h1[row=mt*16+c][cols w*16+q*4+r]
            f16x4 h4;
#pragma unroll
            for (int r = 0; r < 4; ++r) h4[r] = (f16)silu_f(an[r] + bn1q[r]);
            *(f16x4*)&h1lds[mt * 2048 + h1w_base] = h4;
            // gate partial for this stripe
            float p = 0.f;
#pragma unroll
            for (int r = 0; r < 4; ++r)
                p += silu_f(ag[r] + bg1q[r]) * wg2q[r];
            p += __shfl_xor(p, 16);
            p += __shfl_xor(p, 32);
            if (lane < 16) gpart[w][mt * 16 + lane] = p;
        }
        __syncthreads();  // C: gpart + h1lds ready

        // ---- every wave redundantly finalizes gate scores for its rows ----
        float e[4];
#pragma unroll
        for (int mt = 0; mt < 4; ++mt) {
            float g = bg2v;
#pragma unroll
            for (int w2 = 0; w2 < 8; ++w2) g += gpart[w2][mt * 16 + c];
            e[mt] = __expf(g);
        }
        if (w == 0 && q == 0) {
#pragma unroll
            for (int mt = 0; mt < 4; ++mt) Sl += e[mt];
        }

        // ---- n2 (transposed) + weighted V accumulation ----
#pragma unroll
        for (int mt = 0; mt < 4; ++mt) {
            f16x8 b[4];
#pragma unroll
            for (int kc = 0; kc < 4; ++kc)
                b[kc] = *(const f16x8*)&h1lds[(mt * 4 + kc) * 512 +
                                              ((kc & 1) ? loh_o : loh_e)];
            f32x4 acc = {0.f, 0.f, 0.f, 0.f};
#pragma unroll
            for (int kc = 0; kc < 4; ++kc)
                acc = mfma16(fn2[kc], b[kc], acc);
#pragma unroll
            for (int r = 0; r < 4; ++r) V[r] += e[mt] * acc[r];
        }
    }

    // ---- block-level reductions ----
#pragma unroll
    for (int m = 1; m < 16; m <<= 1) {
#pragma unroll
        for (int r = 0; r < 4; ++r) V[r] += __shfl_xor(V[r], m);
    }
    if ((lane & 15) == 0) {
        float4 o = {V[0], V[1], V[2], V[3]};
        *(float4*)&vpart[(long)blockIdx.x * 128 + w * 16 + q * 4] = o;
    }
    if (w == 0) {
#pragma unroll
        for (int m = 1; m < 16; m <<= 1) Sl += __shfl_xor(Sl, m);
        if (lane == 0) spart[blockIdx.x] = Sl;
    }
}

// ---------------------------------------------------------------------------
// K2: combine per-block partials. 32 blocks (batch) x 128 threads (col).
// NBLK/B_ = 32 partials per batch. bn2 folded in (sum attn == 1).
// ---------------------------------------------------------------------------
__global__ void k2_combine(const float* __restrict__ vpart,
                           const float* __restrict__ spart,
                           const float* __restrict__ bn2,
                           float* __restrict__ out) {
    const int b = blockIdx.x;
    const int j = threadIdx.x;
    const int P = NBLK / B_;
    float v = 0.f, s = 0.f;
#pragma unroll
    for (int k = 0; k < P; ++k) {
        v += vpart[(long)(b * P + k) * 128 + j];
        s += spart[b * P + k];
    }
    out[b * 128 + j] = v / s + bn2[j];
}

// ---------------------------------------------------------------------------
extern "C" void kernel_launch(void* const* d_in, const int* in_sizes, int n_in,
                              void* d_out, int out_size, void* d_ws, size_t ws_size,
                              hipStream_t stream) {
    const float* x   = (const float*)d_in[0];
    const float* Wg1 = (const float*)d_in[1];
    const float* bg1 = (const float*)d_in[2];
    const float* Wg2 = (const float*)d_in[3];
    const float* bg2 = (const float*)d_in[4];
    const float* Wn1 = (const float*)d_in[5];
    const float* bn1 = (const float*)d_in[6];
    const float* Wn2 = (const float*)d_in[7];
    const float* bn2 = (const float*)d_in[8];
    float* out = (float*)d_out;

    char* ws = (char*)d_ws;
    f16*   wp    = (f16*)(ws + WPACK_OFF);
    float* vpart = (float*)(ws + VPART_OFF);
    float* spart = (float*)(ws + SPART_OFF);

    k0_prepack<<<192, 256, 0, stream>>>(Wg1, Wn1, Wn2, wp);
    k1_fused<<<NBLK, 512, 0, stream>>>(x, bg1, Wg2, bg2, bn1, wp, vpart, spart);
    k2_combine<<<32, 128, 0, stream>>>(vpart, spart, bn2, out);
}

// Round 4
// 212.140 us; speedup vs baseline: 1.2070x; 1.0429x over previous
//
#include <hip/hip_runtime.h>

// Problem constants
#define B_ 32
#define N_ 8192
#define D_ 128
#define H_ 128
#define R_ (B_ * N_)   // 262144 rows total

#define NBLK 4096      // K1 grid: one 64-row tile per block, 128 blocks/batch

typedef _Float16 f16;
typedef __attribute__((ext_vector_type(4))) _Float16 f16x4;
typedef __attribute__((ext_vector_type(8))) _Float16 f16x8;
typedef __attribute__((ext_vector_type(4))) float f32x4;

// Workspace layout (bytes)
static constexpr size_t WPACK_OFF = 0;                            // 3*128*128 f16
static constexpr size_t VPART_OFF = 98304;                        // NBLK*128 f32 (2 MB)
static constexpr size_t SPART_OFF = VPART_OFF + (size_t)NBLK * 128 * 4;

__device__ __forceinline__ float silu_f(float v) {
    return v * __builtin_amdgcn_rcpf(1.0f + __expf(-v));
}

__device__ __forceinline__ f32x4 mfma16(f16x8 a, f16x8 b, f32x4 c) {
    return __builtin_amdgcn_mfma_f32_16x16x32_f16(a, b, c, 0, 0, 0);
}

// ---------------------------------------------------------------------------
// K0: prepack Wg1, Wn1, Wn2 (fp32 row-major [k][n] 128x128) into fp16 MFMA
// fragment order (A/B symmetric): frag[(nt*4+kc)*64 + lane][j]
//   = W[(kc*32 + (lane>>4)*8 + j)][nt*16 + (lane&15)]
// ---------------------------------------------------------------------------
__global__ void k0_prepack(const float* __restrict__ Wg1,
                           const float* __restrict__ Wn1,
                           const float* __restrict__ Wn2,
                           f16* __restrict__ wp) {
    int tid = blockIdx.x * 256 + threadIdx.x;  // 0..49151
    int m    = tid >> 14;
    int r    = tid & 16383;
    int j    = r & 7;
    int lane = (r >> 3) & 63;
    int kc   = (r >> 9) & 3;
    int nt   = r >> 11;
    int k = kc * 32 + (lane >> 4) * 8 + j;
    int n = nt * 16 + (lane & 15);
    const float* W = (m == 0) ? Wg1 : (m == 1) ? Wn1 : Wn2;
    wp[tid] = (f16)W[k * 128 + n];
}

// ---------------------------------------------------------------------------
// K1: fully fused, one 64-row tile per block. 256 threads = 4 waves; wave w
// owns col-stripes {2w, 2w+1} (32 cols) across ALL 64 rows -> LDS read
// amplification = 4 (was 8). Transposed MFMA (W as A): lane holds
// D[col = st*16+q*4+r][row = mt*16+c].
// Phases: [load x + weights, stage x] B [gate/n1 -> gpart,h1lds] C
//         [finalize exp; n2; V/S partials -> global]
// ---------------------------------------------------------------------------
__global__ __launch_bounds__(256, 2) void k1_fused(
        const float* __restrict__ x,
        const float* __restrict__ bg1, const float* __restrict__ wg2,
        const float* __restrict__ bg2, const float* __restrict__ bn1,
        const f16* __restrict__ wp,
        float* __restrict__ vpart, float* __restrict__ spart) {
    __shared__ f16 xlds[64 * 128];
    __shared__ f16 h1lds[64 * 128];
    __shared__ float gpart[4][64];

    const int tid  = threadIdx.x;
    const int w    = tid >> 6;    // wave id: stripes 2w, 2w+1
    const int lane = tid & 63;
    const int q    = lane >> 4;
    const int c    = lane & 15;

    // ---- issue x tile loads first (8 float4 / thread) ----
    const long rowbase = (long)blockIdx.x * 64;
    const float4* xg = (const float4*)x + rowbase * 32;
    float4 xv[8];
#pragma unroll
    for (int s = 0; s < 8; ++s) xv[s] = xg[s * 256 + tid];

    // ---- weight fragments for this wave's 2 stripes ----
    const f16x8* wpv = (const f16x8*)wp;
    f16x8 fg1[2][4], fn1[2][4], fn2[2][4];
#pragma unroll
    for (int s = 0; s < 2; ++s)
#pragma unroll
        for (int kc = 0; kc < 4; ++kc) {
            int base = ((2 * w + s) * 4 + kc) * 64 + lane;
            fg1[s][kc] = wpv[base];
            fn1[s][kc] = wpv[2048 + base];
            fn2[s][kc] = wpv[4096 + base];
        }
    float bg1q[2][4], wg2q[2][4], bn1q[2][4];
#pragma unroll
    for (int s = 0; s < 2; ++s)
#pragma unroll
        for (int r = 0; r < 4; ++r) {
            int col = (2 * w + s) * 16 + q * 4 + r;
            bg1q[s][r] = bg1[col];
            wg2q[s][r] = wg2[col];
            bn1q[s][r] = bn1[col];
        }
    const float bg2v = bg2[0];

    // Swizzled per-lane LDS read offsets (halves) for A-frag reads
    const int loh_e = (q * 16 + (c ^ q)) * 8;        // kc even
    const int loh_o = (q * 16 + (c ^ (q | 4))) * 8;  // kc odd
    // h1 write bases for stripes st = 2w+s (kc2 = st>>1 = w)
    int h1wb[2];
#pragma unroll
    for (int s = 0; s < 2; ++s) {
        int q2 = s * 2 + (q >> 1);
        int v2 = ((w & 1) << 2) | q2;
        h1wb[s] = w * 512 + (q2 * 16 + (c ^ v2)) * 8 + (q & 1) * 4;
    }

    // ---- stage x tile into swizzled frag-order LDS ----
#pragma unroll
    for (int s = 0; s < 8; ++s) {
        int e   = s * 256 + tid;      // 0..2047 float4s
        int row = e >> 5, c4 = e & 31;
        int mt = row >> 4, cc = row & 15;
        int kc = c4 >> 3, qq = (c4 >> 1) & 3, j = (c4 & 1) * 4;
        int sw = (c4 >> 1) & 7;       // = (kc&1)*4 + qq
        float4 vv = xv[s];
        f16x4 hv = {(f16)vv.x, (f16)vv.y, (f16)vv.z, (f16)vv.w};
        *(f16x4*)&xlds[((mt * 4 + kc) * 64 + qq * 16 + (cc ^ sw)) * 8 + j] = hv;
    }
    __syncthreads();  // B: xlds ready

    // ---- gate1 + n1: per mt, accumulate over kc for both stripes ----
#pragma unroll
    for (int mt = 0; mt < 4; ++mt) {
        f16x8 a[4];
#pragma unroll
        for (int kc = 0; kc < 4; ++kc)
            a[kc] = *(const f16x8*)&xlds[(mt * 4 + kc) * 512 +
                                         ((kc & 1) ? loh_o : loh_e)];
        f32x4 ag[2] = {{0.f,0.f,0.f,0.f},{0.f,0.f,0.f,0.f}};
        f32x4 an[2] = {{0.f,0.f,0.f,0.f},{0.f,0.f,0.f,0.f}};
#pragma unroll
        for (int kc = 0; kc < 4; ++kc) {
#pragma unroll
            for (int s = 0; s < 2; ++s) {
                ag[s] = mfma16(fg1[s][kc], a[kc], ag[s]);
                an[s] = mfma16(fn1[s][kc], a[kc], an[s]);
            }
        }
        // h1: lane holds h1[row=mt*16+c][col=(2w+s)*16+q*4+r]
#pragma unroll
        for (int s = 0; s < 2; ++s) {
            f16x4 h4;
#pragma unroll
            for (int r = 0; r < 4; ++r) h4[r] = (f16)silu_f(an[s][r] + bn1q[s][r]);
            *(f16x4*)&h1lds[mt * 2048 + h1wb[s]] = h4;
        }
        // gate partial over this wave's 32 cols
        float p = 0.f;
#pragma unroll
        for (int s = 0; s < 2; ++s)
#pragma unroll
            for (int r = 0; r < 4; ++r)
                p += silu_f(ag[s][r] + bg1q[s][r]) * wg2q[s][r];
        p += __shfl_xor(p, 16);
        p += __shfl_xor(p, 32);
        if (lane < 16) gpart[w][mt * 16 + lane] = p;
    }
    __syncthreads();  // C: gpart + h1lds ready

    // ---- finalize gate scores (redundant per wave): e for rows mt*16+c ----
    float e4[4];
#pragma unroll
    for (int mt = 0; mt < 4; ++mt) {
        float g = bg2v + gpart[0][mt * 16 + c] + gpart[1][mt * 16 + c]
                       + gpart[2][mt * 16 + c] + gpart[3][mt * 16 + c];
        e4[mt] = __expf(g);
    }

    // ---- n2 + weighted V accumulation ----
    float V[2][4] = {{0.f,0.f,0.f,0.f},{0.f,0.f,0.f,0.f}};
#pragma unroll
    for (int mt = 0; mt < 4; ++mt) {
        f16x8 b[4];
#pragma unroll
        for (int kc = 0; kc < 4; ++kc)
            b[kc] = *(const f16x8*)&h1lds[(mt * 4 + kc) * 512 +
                                          ((kc & 1) ? loh_o : loh_e)];
        f32x4 acc[2] = {{0.f,0.f,0.f,0.f},{0.f,0.f,0.f,0.f}};
#pragma unroll
        for (int kc = 0; kc < 4; ++kc)
#pragma unroll
            for (int s = 0; s < 2; ++s)
                acc[s] = mfma16(fn2[s][kc], b[kc], acc[s]);
#pragma unroll
        for (int s = 0; s < 2; ++s)
#pragma unroll
            for (int r = 0; r < 4; ++r) V[s][r] += e4[mt] * acc[s][r];
    }

    // ---- reduce over rows held by different c-lanes; write partials ----
#pragma unroll
    for (int m = 1; m < 16; m <<= 1)
#pragma unroll
        for (int s = 0; s < 2; ++s)
#pragma unroll
            for (int r = 0; r < 4; ++r) V[s][r] += __shfl_xor(V[s][r], m);
    if (c == 0) {
#pragma unroll
        for (int s = 0; s < 2; ++s) {
            float4 o = {V[s][0], V[s][1], V[s][2], V[s][3]};
            *(float4*)&vpart[(long)blockIdx.x * 128 + (2 * w + s) * 16 + q * 4] = o;
        }
    }
    if (w == 0) {
        float Sl = e4[0] + e4[1] + e4[2] + e4[3];  // rows mt*16+c (q duplicates)
#pragma unroll
        for (int m = 1; m < 16; m <<= 1) Sl += __shfl_xor(Sl, m);
        if (lane == 0) spart[blockIdx.x] = Sl;
    }
}

// ---------------------------------------------------------------------------
// K2: combine per-block partials. 32 blocks (batch) x 256 threads.
// 128 partials per batch; two half-sums per col, then merge.
// ---------------------------------------------------------------------------
__global__ void k2_combine(const float* __restrict__ vpart,
                           const float* __restrict__ spart,
                           const float* __restrict__ bn2,
                           float* __restrict__ out) {
    const int b = blockIdx.x;
    const int t = threadIdx.x;   // 0..255
    const int j = t & 127;
    const int half = t >> 7;

    const float* vp = vpart + (long)b * 128 * 128;
    float v = 0.f;
#pragma unroll
    for (int k = 0; k < 64; ++k)
        v += vp[(half * 64 + k) * 128 + j];

    __shared__ float vred[128];
    __shared__ float sred[4];
    if (half == 0) vred[j] = v;

    // denominator: threads 0..127 (2 waves) hold one spart each
    float s = (t < 128) ? spart[b * 128 + t] : 0.f;
#pragma unroll
    for (int m = 1; m < 64; m <<= 1) s += __shfl_xor(s, m);
    if (t < 128 && (t & 63) == 0) sred[t >> 6] = s;
    __syncthreads();
    if (half == 1) vred[j] += v;
    __syncthreads();
    if (t < 128) {
        float denom = sred[0] + sred[1];
        out[b * 128 + t] = vred[t] / denom + bn2[t];
    }
}

// ---------------------------------------------------------------------------
extern "C" void kernel_launch(void* const* d_in, const int* in_sizes, int n_in,
                              void* d_out, int out_size, void* d_ws, size_t ws_size,
                              hipStream_t stream) {
    const float* x   = (const float*)d_in[0];
    const float* Wg1 = (const float*)d_in[1];
    const float* bg1 = (const float*)d_in[2];
    const float* Wg2 = (const float*)d_in[3];
    const float* bg2 = (const float*)d_in[4];
    const float* Wn1 = (const float*)d_in[5];
    const float* bn1 = (const float*)d_in[6];
    const float* Wn2 = (const float*)d_in[7];
    const float* bn2 = (const float*)d_in[8];
    float* out = (float*)d_out;

    char* ws = (char*)d_ws;
    f16*   wp    = (f16*)(ws + WPACK_OFF);
    float* vpart = (float*)(ws + VPART_OFF);
    float* spart = (float*)(ws + SPART_OFF);

    k0_prepack<<<192, 256, 0, stream>>>(Wg1, Wn1, Wn2, wp);
    k1_fused<<<NBLK, 256, 0, stream>>>(x, bg1, Wg2, bg2, bn1, wp, vpart, spart);
    k2_combine<<<32, 256, 0, stream>>>(vpart, spart, bn2, out);
}

// Round 5
// 211.972 us; speedup vs baseline: 1.2080x; 1.0008x over previous
//
#include <hip/hip_runtime.h>

// Problem constants
#define B_ 32
#define N_ 8192
#define D_ 128
#define H_ 128
#define R_ (B_ * N_)   // 262144 rows total

#define NBLK 4096      // K1 grid: one 64-row tile per block, 128 blocks/batch

typedef _Float16 f16;
typedef __attribute__((ext_vector_type(4))) _Float16 f16x4;
typedef __attribute__((ext_vector_type(8))) _Float16 f16x8;
typedef __attribute__((ext_vector_type(4))) float f32x4;

// Workspace layout (bytes)
static constexpr size_t WPACK_OFF = 0;                            // 3*128*128 f16
static constexpr size_t VPART_OFF = 98304;                        // NBLK*128 f32 (2 MB)
static constexpr size_t SPART_OFF = VPART_OFF + (size_t)NBLK * 128 * 4;

__device__ __forceinline__ float silu_f(float v) {
    return v * __builtin_amdgcn_rcpf(1.0f + __expf(-v));
}

__device__ __forceinline__ f32x4 mfma16(f16x8 a, f16x8 b, f32x4 c) {
    return __builtin_amdgcn_mfma_f32_16x16x32_f16(a, b, c, 0, 0, 0);
}

// ---------------------------------------------------------------------------
// K0: prepack Wg1, Wn1, Wn2 (fp32 row-major [k][n] 128x128) into fp16 MFMA
// fragment order (A/B symmetric): frag[(nt*4+kc)*64 + lane][j]
//   = W[(kc*32 + (lane>>4)*8 + j)][nt*16 + (lane&15)]
// ---------------------------------------------------------------------------
__global__ void k0_prepack(const float* __restrict__ Wg1,
                           const float* __restrict__ Wn1,
                           const float* __restrict__ Wn2,
                           f16* __restrict__ wp) {
    int tid = blockIdx.x * 256 + threadIdx.x;  // 0..49151
    int m    = tid >> 14;
    int r    = tid & 16383;
    int j    = r & 7;
    int lane = (r >> 3) & 63;
    int kc   = (r >> 9) & 3;
    int nt   = r >> 11;
    int k = kc * 32 + (lane >> 4) * 8 + j;
    int n = nt * 16 + (lane & 15);
    const float* W = (m == 0) ? Wg1 : (m == 1) ? Wn1 : Wn2;
    wp[tid] = (f16)W[k * 128 + n];
}

// ---------------------------------------------------------------------------
// K1: fully fused, one 64-row tile per block. 256 threads = 4 waves; wave w
// owns col-stripes {2w, 2w+1}. Transposed MFMA (W as A): lane holds
// D[col = st*16+q*4+r][row = mt*16+c].
// VGPR discipline for 3 blocks/CU: fg1/fn1 resident from preamble (64);
// fn2 (32) issued at END of phase 1 so its L2 latency hides behind
// barrier C + gate finalize; xv[8] (32) dead after staging.
// Phases: [load x + fg1/fn1 + biases, stage x] B [gate/n1 -> gpart,h1lds;
//          issue fn2 loads] C [finalize exp; n2; V/S partials -> global]
// ---------------------------------------------------------------------------
__global__ __launch_bounds__(256, 3) void k1_fused(
        const float* __restrict__ x,
        const float* __restrict__ bg1, const float* __restrict__ wg2,
        const float* __restrict__ bg2, const float* __restrict__ bn1,
        const f16* __restrict__ wp,
        float* __restrict__ vpart, float* __restrict__ spart) {
    __shared__ f16 xlds[64 * 128];
    __shared__ f16 h1lds[64 * 128];
    __shared__ float gpart[4][64];

    const int tid  = threadIdx.x;
    const int w    = tid >> 6;    // wave id: stripes 2w, 2w+1
    const int lane = tid & 63;
    const int q    = lane >> 4;
    const int c    = lane & 15;

    // ---- issue x tile loads first (8 float4 / thread) ----
    const long rowbase = (long)blockIdx.x * 64;
    const float4* xg = (const float4*)x + rowbase * 32;
    float4 xv[8];
#pragma unroll
    for (int s = 0; s < 8; ++s) xv[s] = xg[s * 256 + tid];

    // ---- phase-1 weight fragments (fg1, fn1 only; fn2 comes later) ----
    const f16x8* wpv = (const f16x8*)wp;
    f16x8 fg1[2][4], fn1[2][4];
#pragma unroll
    for (int s = 0; s < 2; ++s)
#pragma unroll
        for (int kc = 0; kc < 4; ++kc) {
            int base = ((2 * w + s) * 4 + kc) * 64 + lane;
            fg1[s][kc] = wpv[base];
            fn1[s][kc] = wpv[2048 + base];
        }
    float bg1q[2][4], wg2q[2][4], bn1q[2][4];
#pragma unroll
    for (int s = 0; s < 2; ++s)
#pragma unroll
        for (int r = 0; r < 4; ++r) {
            int col = (2 * w + s) * 16 + q * 4 + r;
            bg1q[s][r] = bg1[col];
            wg2q[s][r] = wg2[col];
            bn1q[s][r] = bn1[col];
        }
    const float bg2v = bg2[0];

    // Swizzled per-lane LDS read offsets (halves) for A-frag reads
    const int loh_e = (q * 16 + (c ^ q)) * 8;        // kc even
    const int loh_o = (q * 16 + (c ^ (q | 4))) * 8;  // kc odd
    // h1 write bases for stripes st = 2w+s (kc2 = st>>1 = w)
    int h1wb[2];
#pragma unroll
    for (int s = 0; s < 2; ++s) {
        int q2 = s * 2 + (q >> 1);
        int v2 = ((w & 1) << 2) | q2;
        h1wb[s] = w * 512 + (q2 * 16 + (c ^ v2)) * 8 + (q & 1) * 4;
    }

    // ---- stage x tile into swizzled frag-order LDS (xv dies here) ----
#pragma unroll
    for (int s = 0; s < 8; ++s) {
        int e   = s * 256 + tid;      // 0..2047 float4s
        int row = e >> 5, c4 = e & 31;
        int mt = row >> 4, cc = row & 15;
        int kc = c4 >> 3, qq = (c4 >> 1) & 3, j = (c4 & 1) * 4;
        int sw = (c4 >> 1) & 7;       // = (kc&1)*4 + qq
        float4 vv = xv[s];
        f16x4 hv = {(f16)vv.x, (f16)vv.y, (f16)vv.z, (f16)vv.w};
        *(f16x4*)&xlds[((mt * 4 + kc) * 64 + qq * 16 + (cc ^ sw)) * 8 + j] = hv;
    }
    __syncthreads();  // B: xlds ready

    // ---- gate1 + n1: per mt, accumulate over kc for both stripes ----
#pragma unroll
    for (int mt = 0; mt < 4; ++mt) {
        f16x8 a[4];
#pragma unroll
        for (int kc = 0; kc < 4; ++kc)
            a[kc] = *(const f16x8*)&xlds[(mt * 4 + kc) * 512 +
                                         ((kc & 1) ? loh_o : loh_e)];
        f32x4 ag[2] = {{0.f,0.f,0.f,0.f},{0.f,0.f,0.f,0.f}};
        f32x4 an[2] = {{0.f,0.f,0.f,0.f},{0.f,0.f,0.f,0.f}};
#pragma unroll
        for (int kc = 0; kc < 4; ++kc) {
#pragma unroll
            for (int s = 0; s < 2; ++s) {
                ag[s] = mfma16(fg1[s][kc], a[kc], ag[s]);
                an[s] = mfma16(fn1[s][kc], a[kc], an[s]);
            }
        }
        // h1: lane holds h1[row=mt*16+c][col=(2w+s)*16+q*4+r]
#pragma unroll
        for (int s = 0; s < 2; ++s) {
            f16x4 h4;
#pragma unroll
            for (int r = 0; r < 4; ++r) h4[r] = (f16)silu_f(an[s][r] + bn1q[s][r]);
            *(f16x4*)&h1lds[mt * 2048 + h1wb[s]] = h4;
        }
        // gate partial over this wave's 32 cols
        float p = 0.f;
#pragma unroll
        for (int s = 0; s < 2; ++s)
#pragma unroll
            for (int r = 0; r < 4; ++r)
                p += silu_f(ag[s][r] + bg1q[s][r]) * wg2q[s][r];
        p += __shfl_xor(p, 16);
        p += __shfl_xor(p, 32);
        if (lane < 16) gpart[w][mt * 16 + lane] = p;
    }

    // ---- issue fn2 loads now: latency hides behind barrier C + finalize ----
    f16x8 fn2[2][4];
#pragma unroll
    for (int s = 0; s < 2; ++s)
#pragma unroll
        for (int kc = 0; kc < 4; ++kc)
            fn2[s][kc] = wpv[4096 + ((2 * w + s) * 4 + kc) * 64 + lane];

    __syncthreads();  // C: gpart + h1lds ready

    // ---- finalize gate scores (redundant per wave): e for rows mt*16+c ----
    float e4[4];
#pragma unroll
    for (int mt = 0; mt < 4; ++mt) {
        float g = bg2v + gpart[0][mt * 16 + c] + gpart[1][mt * 16 + c]
                       + gpart[2][mt * 16 + c] + gpart[3][mt * 16 + c];
        e4[mt] = __expf(g);
    }

    // ---- n2 + weighted V accumulation ----
    float V[2][4] = {{0.f,0.f,0.f,0.f},{0.f,0.f,0.f,0.f}};
#pragma unroll
    for (int mt = 0; mt < 4; ++mt) {
        f16x8 b[4];
#pragma unroll
        for (int kc = 0; kc < 4; ++kc)
            b[kc] = *(const f16x8*)&h1lds[(mt * 4 + kc) * 512 +
                                          ((kc & 1) ? loh_o : loh_e)];
        f32x4 acc[2] = {{0.f,0.f,0.f,0.f},{0.f,0.f,0.f,0.f}};
#pragma unroll
        for (int kc = 0; kc < 4; ++kc)
#pragma unroll
            for (int s = 0; s < 2; ++s)
                acc[s] = mfma16(fn2[s][kc], b[kc], acc[s]);
#pragma unroll
        for (int s = 0; s < 2; ++s)
#pragma unroll
            for (int r = 0; r < 4; ++r) V[s][r] += e4[mt] * acc[s][r];
    }

    // ---- reduce over rows held by different c-lanes; write partials ----
#pragma unroll
    for (int m = 1; m < 16; m <<= 1)
#pragma unroll
        for (int s = 0; s < 2; ++s)
#pragma unroll
            for (int r = 0; r < 4; ++r) V[s][r] += __shfl_xor(V[s][r], m);
    if (c == 0) {
#pragma unroll
        for (int s = 0; s < 2; ++s) {
            float4 o = {V[s][0], V[s][1], V[s][2], V[s][3]};
            *(float4*)&vpart[(long)blockIdx.x * 128 + (2 * w + s) * 16 + q * 4] = o;
        }
    }
    if (w == 0) {
        float Sl = e4[0] + e4[1] + e4[2] + e4[3];  // rows mt*16+c (q duplicates)
#pragma unroll
        for (int m = 1; m < 16; m <<= 1) Sl += __shfl_xor(Sl, m);
        if (lane == 0) spart[blockIdx.x] = Sl;
    }
}

// ---------------------------------------------------------------------------
// K2: combine per-block partials. 32 blocks (batch) x 256 threads.
// 128 partials per batch; two half-sums per col, then merge.
// ---------------------------------------------------------------------------
__global__ void k2_combine(const float* __restrict__ vpart,
                           const float* __restrict__ spart,
                           const float* __restrict__ bn2,
                           float* __restrict__ out) {
    const int b = blockIdx.x;
    const int t = threadIdx.x;   // 0..255
    const int j = t & 127;
    const int half = t >> 7;

    const float* vp = vpart + (long)b * 128 * 128;
    float v = 0.f;
#pragma unroll
    for (int k = 0; k < 64; ++k)
        v += vp[(half * 64 + k) * 128 + j];

    __shared__ float vred[128];
    __shared__ float sred[4];
    if (half == 0) vred[j] = v;

    // denominator: threads 0..127 (2 waves) hold one spart each
    float s = (t < 128) ? spart[b * 128 + t] : 0.f;
#pragma unroll
    for (int m = 1; m < 64; m <<= 1) s += __shfl_xor(s, m);
    if (t < 128 && (t & 63) == 0) sred[t >> 6] = s;
    __syncthreads();
    if (half == 1) vred[j] += v;
    __syncthreads();
    if (t < 128) {
        float denom = sred[0] + sred[1];
        out[b * 128 + t] = vred[t] / denom + bn2[t];
    }
}

// ---------------------------------------------------------------------------
extern "C" void kernel_launch(void* const* d_in, const int* in_sizes, int n_in,
                              void* d_out, int out_size, void* d_ws, size_t ws_size,
                              hipStream_t stream) {
    const float* x   = (const float*)d_in[0];
    const float* Wg1 = (const float*)d_in[1];
    const float* bg1 = (const float*)d_in[2];
    const float* Wg2 = (const float*)d_in[3];
    const float* bg2 = (const float*)d_in[4];
    const float* Wn1 = (const float*)d_in[5];
    const float* bn1 = (const float*)d_in[6];
    const float* Wn2 = (const float*)d_in[7];
    const float* bn2 = (const float*)d_in[8];
    float* out = (float*)d_out;

    char* ws = (char*)d_ws;
    f16*   wp    = (f16*)(ws + WPACK_OFF);
    float* vpart = (float*)(ws + VPART_OFF);
    float* spart = (float*)(ws + SPART_OFF);

    k0_prepack<<<192, 256, 0, stream>>>(Wg1, Wn1, Wn2, wp);
    k1_fused<<<NBLK, 256, 0, stream>>>(x, bg1, Wg2, bg2, bn1, wp, vpart, spart);
    k2_combine<<<32, 256, 0, stream>>>(vpart, spart, bn2, out);
}